// Round 4
// baseline (69.898 us; speedup 1.0000x reference)
//
#include <hip/hip_runtime.h>

#ifndef __has_builtin
#define __has_builtin(x) 0
#endif

#if __has_builtin(__builtin_amdgcn_exp2f)
#define EXP2F(x) __builtin_amdgcn_exp2f(x)
#else
#define EXP2F(x) exp2f(x)
#endif
#if __has_builtin(__builtin_amdgcn_rcpf)
#define RCPF(x) __builtin_amdgcn_rcpf(x)
#else
#define RCPF(x) (1.0f / (x))
#endif

static constexpr int NB = 4, NQ = 512, NK = 512, DD = 512, HH = 128, DV = 512;
static constexpr float MASKV = -1e6f;
static constexpr float C2LOG2E = 2.885390081777926814f;  // 2*log2(e)

// ---------------------------------------------------------------------------
// K1: tiled GEMM for both projections, stacked rows (0..2047 q, 2048.. keys).
// 8-way K-split, tile 64x128, 256 thr, 4x8 micro-tile. Masked key tiles skip.
// ---------------------------------------------------------------------------
__global__ __launch_bounds__(256) void proj_gemm_kernel(
    const float* __restrict__ queries, const float* __restrict__ keys,
    const float* __restrict__ Wq, const float* __restrict__ Wk,
    const int* __restrict__ valid_lens, float* __restrict__ projpart) {
  const int mt = blockIdx.x >> 3;
  const int ks = blockIdx.x & 7;
  const int row0 = mt << 6;
  const int k0 = ks << 6;
  const float* inb;
  const float* W;
  if (row0 >= 2048) {
    const int local = row0 - 2048;
    if ((local & 511) >= valid_lens[local >> 9]) return;  // never consumed
    inb = keys + (size_t)local * DD;
    W = Wk;
  } else {
    inb = queries + (size_t)row0 * DD;
    W = Wq;
  }

  __shared__ float aS[64][65];
  __shared__ __align__(16) float bS[64][128];

  const int t = threadIdx.x;
#pragma unroll
  for (int f = 0; f < 4; ++f) {
    const int idx = t + (f << 8);
    const int r = idx >> 4, d0 = (idx & 15) << 2;
    const float4 v = *reinterpret_cast<const float4*>(inb + (size_t)r * DD + k0 + d0);
    aS[r][d0] = v.x; aS[r][d0 + 1] = v.y; aS[r][d0 + 2] = v.z; aS[r][d0 + 3] = v.w;
  }
#pragma unroll
  for (int f = 0; f < 8; ++f) {
    const int idx = t + (f << 8);
    const int dk = idx >> 5, c4 = (idx & 31) << 2;
    *reinterpret_cast<float4*>(&bS[dk][c4]) =
        *reinterpret_cast<const float4*>(W + (size_t)(k0 + dk) * HH + c4);
  }
  __syncthreads();

  const int tv = t & 15, tr = t >> 4;
  float acc[4][8];
#pragma unroll
  for (int i = 0; i < 4; ++i)
#pragma unroll
    for (int j = 0; j < 8; ++j) acc[i][j] = 0.f;

#pragma unroll 8
  for (int dk = 0; dk < 64; ++dk) {
    const float av[4] = {aS[(tr << 2) + 0][dk], aS[(tr << 2) + 1][dk],
                         aS[(tr << 2) + 2][dk], aS[(tr << 2) + 3][dk]};
    const float4 b0 = *reinterpret_cast<const float4*>(&bS[dk][tv << 2]);
    const float4 b1 = *reinterpret_cast<const float4*>(&bS[dk][64 + (tv << 2)]);
    const float bv[8] = {b0.x, b0.y, b0.z, b0.w, b1.x, b1.y, b1.z, b1.w};
#pragma unroll
    for (int i = 0; i < 4; ++i)
#pragma unroll
      for (int j = 0; j < 8; ++j) acc[i][j] = fmaf(av[i], bv[j], acc[i][j]);
  }

  float* pb = projpart + ((size_t)ks << 19) + (size_t)row0 * HH;
#pragma unroll
  for (int i = 0; i < 4; ++i) {
    float* rowp = pb + (size_t)((tr << 2) + i) * HH;
    *reinterpret_cast<float4*>(rowp + (tv << 2)) =
        make_float4(acc[i][0], acc[i][1], acc[i][2], acc[i][3]);
    *reinterpret_cast<float4*>(rowp + 64 + (tv << 2)) =
        make_float4(acc[i][4], acc[i][5], acc[i][6], acc[i][7]);
  }
}

// ---------------------------------------------------------------------------
// K2: epk[row][h] = exp2( C * sum_{ks<8} projpart[ks][row][h] )
// ---------------------------------------------------------------------------
__global__ __launch_bounds__(256) void proj_reduce_kernel(
    const float* __restrict__ projpart, float* __restrict__ epk) {
  const int i = blockIdx.x * 256 + threadIdx.x;
  const float4* p = reinterpret_cast<const float4*>(projpart);
  float4 s = p[i];
#pragma unroll
  for (int j = 1; j < 8; ++j) {
    const float4 v = p[i + j * 131072];
    s.x += v.x; s.y += v.y; s.z += v.z; s.w += v.w;
  }
  float4 r;
  r.x = EXP2F(s.x * C2LOG2E);
  r.y = EXP2F(s.y * C2LOG2E);
  r.z = EXP2F(s.z * C2LOG2E);
  r.w = EXP2F(s.w * C2LOG2E);
  reinterpret_cast<float4*>(epk)[i] = r;
}

// ---------------------------------------------------------------------------
// K3: scores + masked softmax. 1024 blocks, q-tile = 2 rows, b = bid>>8 so
// every CU gets one block from EACH batch (valid_len load balance).
// score = -2 * sum_h w_h / (1 + eq*ek)   (softmax shift-invariance drops sw)
// Writes attnT[b][k][q] (k-major).
// ---------------------------------------------------------------------------
__global__ __launch_bounds__(512) void scores_softmax_kernel(
    const float* __restrict__ eq, const float* __restrict__ ek,
    const float* __restrict__ Wv, const int* __restrict__ valid_lens,
    float* __restrict__ attnT) {
  const int b = blockIdx.x >> 8;
  const int q0 = (blockIdx.x & 255) << 1;
  const int t = threadIdx.x;

  __shared__ __align__(16) float qs[2][HH];
  __shared__ __align__(16) float wv[HH];
  __shared__ float sc[2][NK];

  if (t < 256) {
    qs[t >> 7][t & 127] = eq[((size_t)(b * NQ + q0 + (t >> 7))) * HH + (t & 127)];
  } else if (t < 384) {
    wv[t - 256] = Wv[t - 256];
  }
  __syncthreads();

  const int vl = valid_lens[b];
  float s0 = 0.f, s1 = 0.f;

  if (t < vl) {
    const float* ekrow = ek + ((size_t)(b * NK + t)) * HH;
#pragma unroll 4
    for (int hs = 0; hs < HH; hs += 4) {
      const float4 k4 = *reinterpret_cast<const float4*>(ekrow + hs);
      const float4 w4 = *reinterpret_cast<const float4*>(&wv[hs]);
      const float4 qa = *reinterpret_cast<const float4*>(&qs[0][hs]);
      const float4 qb = *reinterpret_cast<const float4*>(&qs[1][hs]);
      float d, r;
      d = fmaf(qa.x, k4.x, 1.f); r = RCPF(d); s0 = fmaf(w4.x, r, s0);
      d = fmaf(qa.y, k4.y, 1.f); r = RCPF(d); s0 = fmaf(w4.y, r, s0);
      d = fmaf(qa.z, k4.z, 1.f); r = RCPF(d); s0 = fmaf(w4.z, r, s0);
      d = fmaf(qa.w, k4.w, 1.f); r = RCPF(d); s0 = fmaf(w4.w, r, s0);
      d = fmaf(qb.x, k4.x, 1.f); r = RCPF(d); s1 = fmaf(w4.x, r, s1);
      d = fmaf(qb.y, k4.y, 1.f); r = RCPF(d); s1 = fmaf(w4.y, r, s1);
      d = fmaf(qb.z, k4.z, 1.f); r = RCPF(d); s1 = fmaf(w4.z, r, s1);
      d = fmaf(qb.w, k4.w, 1.f); r = RCPF(d); s1 = fmaf(w4.w, r, s1);
    }
  }
  sc[0][t] = (t < vl) ? (-2.f * s0) : MASKV;
  sc[1][t] = (t < vl) ? (-2.f * s1) : MASKV;
  __syncthreads();

  // softmax: wave w (<2) handles q-row w over all 512 keys
  const int w = t >> 6, l = t & 63;
  if (w < 2) {
    float v[8];
#pragma unroll
    for (int j = 0; j < 8; ++j) v[j] = sc[w][l + (j << 6)];
    float m = v[0];
#pragma unroll
    for (int j = 1; j < 8; ++j) m = fmaxf(m, v[j]);
#pragma unroll
    for (int off = 32; off > 0; off >>= 1) m = fmaxf(m, __shfl_xor(m, off, 64));
    float p[8], sum = 0.f;
#pragma unroll
    for (int j = 0; j < 8; ++j) {
      p[j] = __expf(v[j] - m);  // masked: underflows to exactly 0
      sum += p[j];
    }
#pragma unroll
    for (int off = 32; off > 0; off >>= 1) sum += __shfl_xor(sum, off, 64);
    const float inv = RCPF(sum);
#pragma unroll
    for (int j = 0; j < 8; ++j) sc[w][l + (j << 6)] = p[j] * inv;
  }
  __syncthreads();

  *reinterpret_cast<float2*>(attnT + ((size_t)(b * NK + t)) * NQ + q0) =
      make_float2(sc[0][t], sc[1][t]);
}

// ---------------------------------------------------------------------------
// K4: partial[ks][b][q][v] = sum_{k in split} attnT[b][k][q]*values[b][k][v]
// 1024 blocks: 64x64 tiles x 4 ks x 4 b; b = bid>>8 (all batches per CU) and
// ks rotated by b (all mask positions per CU). 256 thr, 4x4 micro, BK=32.
// Inactive splits still write zeros (reduce reads all slices).
// ---------------------------------------------------------------------------
__global__ __launch_bounds__(256) void pv_gemm_kernel(
    const float* __restrict__ attnT, const float* __restrict__ values,
    const int* __restrict__ valid_lens, float* __restrict__ partial) {
  const int bid = blockIdx.x;
  const int b = bid >> 8;
  const int tile = (bid >> 2) & 63;
  const int ks = (bid + b) & 3;      // rotate: each CU covers all 4 ks
  const int q0 = (tile >> 3) << 6;
  const int v0 = (tile & 7) << 6;
  const int kbase = ks << 7;

  __shared__ __align__(16) float aT[32][64];
  __shared__ __align__(16) float bS[32][64];

  const int t = threadIdx.x;
  const int tv = t & 15, tq = t >> 4;

  float acc[4][4];
#pragma unroll
  for (int i = 0; i < 4; ++i)
#pragma unroll
    for (int j = 0; j < 4; ++j) acc[i][j] = 0.f;

  if (kbase < valid_lens[b]) {
    for (int kt = 0; kt < 4; ++kt) {
      const int k0 = kbase + (kt << 5);
#pragma unroll
      for (int f = 0; f < 2; ++f) {
        const int id = t + (f << 8);
        const int dk = id >> 4, c4 = (id & 15) << 2;
        *reinterpret_cast<float4*>(&aT[dk][c4]) =
            *reinterpret_cast<const float4*>(attnT + ((size_t)(b * NK + k0 + dk)) * NQ + q0 + c4);
        *reinterpret_cast<float4*>(&bS[dk][c4]) =
            *reinterpret_cast<const float4*>(values + ((size_t)(b * NK + k0 + dk)) * DV + v0 + c4);
      }
      __syncthreads();
#pragma unroll
      for (int dk = 0; dk < 32; ++dk) {
        const float4 a4 = *reinterpret_cast<const float4*>(&aT[dk][tq << 2]);
        const float4 b4 = *reinterpret_cast<const float4*>(&bS[dk][tv << 2]);
        const float av[4] = {a4.x, a4.y, a4.z, a4.w};
        const float bv[4] = {b4.x, b4.y, b4.z, b4.w};
#pragma unroll
        for (int i = 0; i < 4; ++i)
#pragma unroll
          for (int j = 0; j < 4; ++j) acc[i][j] = fmaf(av[i], bv[j], acc[i][j]);
      }
      __syncthreads();
    }
  }

  float* pbase = partial + ((size_t)(ks * NB + b)) * NQ * DV;
#pragma unroll
  for (int i = 0; i < 4; ++i) {
    float* row = pbase + ((size_t)(q0 + (tq << 2) + i)) * DV + v0;
    *reinterpret_cast<float4*>(row + (tv << 2)) =
        make_float4(acc[i][0], acc[i][1], acc[i][2], acc[i][3]);
  }
}

// ---------------------------------------------------------------------------
// K5: out = sum of the 4 K-split partials
// ---------------------------------------------------------------------------
__global__ __launch_bounds__(256) void reduce4_kernel(
    const float* __restrict__ partial, float* __restrict__ out) {
  const int i = blockIdx.x * 256 + threadIdx.x;
  const float4* p = reinterpret_cast<const float4*>(partial);
  const float4 a = p[i];
  const float4 b = p[i + 262144];
  const float4 c = p[i + 524288];
  const float4 d = p[i + 786432];
  float4 r;
  r.x = a.x + b.x + c.x + d.x;
  r.y = a.y + b.y + c.y + d.y;
  r.z = a.z + b.z + c.z + d.z;
  r.w = a.w + b.w + c.w + d.w;
  reinterpret_cast<float4*>(out)[i] = r;
}

extern "C" void kernel_launch(void* const* d_in, const int* in_sizes, int n_in,
                              void* d_out, int out_size, void* d_ws, size_t ws_size,
                              hipStream_t stream) {
  (void)in_sizes; (void)n_in; (void)out_size; (void)ws_size;
  const float* queries = (const float*)d_in[0];
  const float* keys    = (const float*)d_in[1];
  const float* values  = (const float*)d_in[2];
  const float* Wq      = (const float*)d_in[3];
  const float* Wk      = (const float*)d_in[4];
  const float* Wv      = (const float*)d_in[5];
  const int*   vlens   = (const int*)d_in[6];
  float* out = (float*)d_out;
  float* ws = (float*)d_ws;

  // ws floats: epk 524288 | attnT 1048576 | pvpart 4194304 | projpart 4194304
  float* epk      = ws;
  float* eq       = epk;
  float* ek       = epk + 262144;
  float* attnT    = ws + 524288;
  float* pvpart   = ws + 1572864;
  float* projpart = ws + 5767168;

  proj_gemm_kernel<<<512, 256, 0, stream>>>(queries, keys, Wq, Wk, vlens, projpart);
  proj_reduce_kernel<<<512, 256, 0, stream>>>(projpart, epk);
  scores_softmax_kernel<<<1024, 512, 0, stream>>>(eq, ek, Wv, vlens, attnT);
  pv_gemm_kernel<<<1024, 256, 0, stream>>>(attnT, values, vlens, pvpart);
  reduce4_kernel<<<1024, 256, 0, stream>>>(pvpart, out);
}